// Round 15
// baseline (137.649 us; speedup 1.0000x reference)
//
#include <hip/hip_runtime.h>
#include <hip/hip_bf16.h>
#include <math.h>

// Round 15:
//  - GEMMs: depth-2 pipeline with 3 LDS buffers + counted vmcnt(12) raw-barrier
//    (round-14's depth-1 covered only ~1 compute phase of load latency).
//  - gemm_out widened to BM=128/BN=64 (same step shape as qkvt).
//  - XCD-chunked swizzle + fused zero_pad kept. swattn5/split5 byte-identical.

typedef __attribute__((ext_vector_type(8))) short bf16frag;   // 8 bf16 = 16 B
typedef __attribute__((ext_vector_type(4))) float f32x4;
typedef __attribute__((ext_vector_type(8))) unsigned short u16x8;

#if defined(__has_builtin)
#if __has_builtin(__builtin_amdgcn_global_load_lds)
#define HAVE_GLOAD_LDS 1
#endif
#endif

__device__ inline void gload16(const void* g, void* l, int lane) {
#ifdef HAVE_GLOAD_LDS
    __builtin_amdgcn_global_load_lds(
        (const __attribute__((address_space(1))) void*)g,
        (__attribute__((address_space(3))) void*)l, 16, 0, 0);
#else
    *(bf16frag*)((char*)l + lane * 16) = *(const bf16frag*)g;
#endif
}

__device__ inline unsigned short bf16_rne(float f) {
    unsigned int u = __float_as_uint(f);
    unsigned int r = u + 0x7fffu + ((u >> 16) & 1u);
    return (unsigned short)(r >> 16);
}

__device__ inline void split_val(float f, unsigned short& h, unsigned short& l) {
    h = bf16_rne(f);
    float hf = __uint_as_float(((unsigned int)h) << 16);
    float lf = f - hf;
    l = bf16_rne(lf);
}

// ---- fp32 -> (hi, lo) bf16 split: x + 4 weight matrices in one launch ----
__global__ __launch_bounds__(256) void split5(
    const float* __restrict__ x, const float* __restrict__ wq, const float* __restrict__ wk,
    const float* __restrict__ wv, const float* __restrict__ wo,
    unsigned short* xh, unsigned short* xl, unsigned short* qh, unsigned short* ql,
    unsigned short* kh, unsigned short* kl, unsigned short* vh, unsigned short* vl,
    unsigned short* oh, unsigned short* ol, int nx, int nw)
{
    const float* src; unsigned short *H, *L; int n;
    switch (blockIdx.z) {
        case 0: src = x;  H = xh; L = xl; n = nx; break;
        case 1: src = wq; H = qh; L = ql; n = nw; break;
        case 2: src = wk; H = kh; L = kl; n = nw; break;
        case 3: src = wv; H = vh; L = vl; n = nw; break;
        default: src = wo; H = oh; L = ol; n = nw; break;
    }
    int stride = gridDim.x * blockDim.x * 4;
    for (int i = (blockIdx.x * blockDim.x + threadIdx.x) * 4; i < n; i += stride) {
        float4 f = *(const float4*)(src + i);
        ushort4 h4, l4;
        split_val(f.x, h4.x, l4.x);
        split_val(f.y, h4.y, l4.y);
        split_val(f.z, h4.z, l4.z);
        split_val(f.w, h4.w, l4.w);
        *(ushort4*)(H + i) = h4;
        *(ushort4*)(L + i) = l4;
    }
}

// ---- fused Q/K/V^T projection GEMM, depth-2 pipeline, split-bf16 K-concat ----
// BM=128 x BN=64, BK=64, 24 K-steps ([Ah|Ah|Al] @ [Bh|Bl|Bh]).
__global__ __launch_bounds__(256) void gemm_qkvt(
    const unsigned short* __restrict__ xh, const unsigned short* __restrict__ xl,
    const unsigned short* __restrict__ wqh, const unsigned short* __restrict__ wql,
    const unsigned short* __restrict__ wkh, const unsigned short* __restrict__ wkl,
    const unsigned short* __restrict__ wvh, const unsigned short* __restrict__ wvl,
    unsigned short* __restrict__ QHo, unsigned short* __restrict__ QLo,
    unsigned short* __restrict__ KHo, unsigned short* __restrict__ KLo,
    unsigned short* __restrict__ VTH, unsigned short* __restrict__ VTL,
    int T, int vtw)
{
    constexpr int ABYTES = 128 * 128;                  // A tile bytes
    constexpr int TBYTES = (128 + 64) * 128;           // 24 KB per buffer
    __shared__ unsigned char lds[3][TBYTES];           // 72 KB, depth-2 pipeline

    const int tid  = threadIdx.x;
    const int wid  = tid >> 6;
    const int lane = tid & 63;
    const int wr = wid >> 1, wc = wid & 1;

    // XCD-chunked bijective swizzle (gridDim.x % 8 == 0)
    const int chunk = gridDim.x >> 3;
    const int id = (blockIdx.x & 7) * chunk + (blockIdx.x >> 3);

    const int NQK = 8 * (T / 128);
    const unsigned short *Ah, *Al, *Bh, *Bl;
    unsigned short *OH_, *OL_;
    int m0, n0;
    bool vt;
    if (id < 2 * NQK) {
        vt = false;
        const int zq  = id / NQK;
        const int rem = id % NQK;
        n0 = (rem & 7) * 64;
        m0 = (rem >> 3) * 128;
        Ah = xh; Al = xl;
        Bh = zq ? wkh : wqh;  Bl = zq ? wkl : wql;
        OH_ = zq ? KHo : QHo; OL_ = zq ? KLo : QLo;
    } else {
        vt = true;
        const int rem = id - 2 * NQK;
        const int nx  = T / 64;
        n0 = (rem % nx) * 64;
        m0 = (rem / nx) * 128;
        Ah = wvh; Al = wvl;
        Bh = xh;  Bl = xl;
        OH_ = VTH; OL_ = VTL;
        if (n0 == 0) {                      // fused zero_pad
            for (int i = tid; i < 128 * 63; i += 256) {
                const int r = i / 63, c = i % 63;
                VTH[(size_t)(m0 + r) * vtw + c] = 0;
                VTL[(size_t)(m0 + r) * vtw + c] = 0;
            }
        }
    }

    f32x4 acc[4][2];
    #pragma unroll
    for (int i = 0; i < 4; ++i) {
        acc[i][0] = (f32x4){0.f, 0.f, 0.f, 0.f};
        acc[i][1] = (f32x4){0.f, 0.f, 0.f, 0.f};
    }

    auto stage = [&](int buf, int ks) {
        const int rg = ks >> 3;
        const int k0 = (ks & 7) << 6;
        const unsigned short* As = (rg < 2) ? Ah : Al;
        const unsigned short* Bs = (rg == 1) ? Bl : Bh;
        #pragma unroll
        for (int j = 0; j < 6; ++j) {                  // 24 insts / 4 waves
            const int o  = (wid * 6 + j) << 10;
            const int li = o + lane * 16;
            const void* g;
            if (li < ABYTES) {
                const int r  = li >> 7;
                const int kb = (li & 127) ^ ((r & 7) << 4);   // inverse swizzle
                g = As + (size_t)(m0 + r) * 512 + k0 + (kb >> 1);
            } else {
                const int lb = li - ABYTES;
                const int r  = lb >> 7;
                const int kb = (lb & 127) ^ ((r & 7) << 4);
                g = Bs + (size_t)(n0 + r) * 512 + k0 + (kb >> 1);
            }
            gload16(g, &lds[buf][o], lane);
        }
    };

    // depth-2: tiles ks+1, ks+2 in flight across the barrier; vmcnt(12) waits
    // only for tile ks's 6 loads (issued 2 compute phases earlier).
    stage(0, 0);
    stage(1, 1);
    for (int ks = 0; ks < 24; ++ks) {
        const int cur = ks % 3;
        if (ks < 22) {
            stage((ks + 2) % 3, ks + 2);
            asm volatile("s_waitcnt vmcnt(12)" ::: "memory");
        } else if (ks == 22) {
            asm volatile("s_waitcnt vmcnt(6)" ::: "memory");
        } else {
            asm volatile("s_waitcnt vmcnt(0)" ::: "memory");
        }
        __builtin_amdgcn_s_barrier();      // all waves' tile-ks loads landed
        #pragma unroll
        for (int ksub = 0; ksub < 2; ++ksub) {
            const int kbb = (ksub << 6) + ((lane >> 4) << 4);
            bf16frag af[4], bf[2];
            #pragma unroll
            for (int mt = 0; mt < 4; ++mt) {
                const int r = wr * 64 + mt * 16 + (lane & 15);
                af[mt] = *(const bf16frag*)(&lds[cur][0] + r * 128 + (kbb ^ ((r & 7) << 4)));
            }
            #pragma unroll
            for (int nt = 0; nt < 2; ++nt) {
                const int r = wc * 32 + nt * 16 + (lane & 15);
                bf[nt] = *(const bf16frag*)(&lds[cur][0] + ABYTES + r * 128 + (kbb ^ ((r & 7) << 4)));
            }
            #pragma unroll
            for (int mt = 0; mt < 4; ++mt)
                #pragma unroll
                for (int nt = 0; nt < 2; ++nt)
                    acc[mt][nt] = __builtin_amdgcn_mfma_f32_16x16x32_bf16(
                        af[mt], bf[nt], acc[mt][nt], 0, 0, 0);
        }
        __builtin_amdgcn_s_barrier();      // readers done before buf reuse
    }

    // C/D layout (HW-verified): col = lane&15, row = (lane>>4)*4 + j
    const int rbase = (lane >> 4) * 4;
    #pragma unroll
    for (int mt = 0; mt < 4; ++mt)
        #pragma unroll
        for (int nt = 0; nt < 2; ++nt) {
            const int col = n0 + wc * 32 + nt * 16 + (lane & 15);
            #pragma unroll
            for (int j = 0; j < 4; ++j) {
                const int row = m0 + wr * 64 + mt * 16 + rbase + j;
                unsigned short hh, ll;
                split_val(acc[mt][nt][j], hh, ll);
                if (!vt) {
                    OH_[(size_t)row * 512 + col] = hh;
                    OL_[(size_t)row * 512 + col] = ll;
                } else {
                    OH_[(size_t)row * vtw + 63 + col] = hh;
                    OL_[(size_t)row * vtw + 63 + col] = ll;
                }
            }
        }
}

// ---- output projection GEMM: BM=128/BN=64, depth-2 pipeline, fp32 out ----
__global__ __launch_bounds__(256) void gemm_out(
    const unsigned short* __restrict__ Ah, const unsigned short* __restrict__ Al,
    const unsigned short* __restrict__ Wh, const unsigned short* __restrict__ Wl,
    float* __restrict__ C, int T)
{
    constexpr int ABYTES = 128 * 128;
    constexpr int TBYTES = (128 + 64) * 128;
    __shared__ unsigned char lds[3][TBYTES];

    const int tid  = threadIdx.x;
    const int wid  = tid >> 6;
    const int lane = tid & 63;
    const int wr = wid >> 1, wc = wid & 1;

    const int chunk = gridDim.x >> 3;
    const int b = (blockIdx.x & 7) * chunk + (blockIdx.x >> 3);
    const int n0 = (b & 7) * 64;        // 8 n-blocks share the A-tile
    const int m0 = (b >> 3) * 128;

    f32x4 acc[4][2];
    #pragma unroll
    for (int i = 0; i < 4; ++i) {
        acc[i][0] = (f32x4){0.f, 0.f, 0.f, 0.f};
        acc[i][1] = (f32x4){0.f, 0.f, 0.f, 0.f};
    }

    auto stage = [&](int buf, int ks) {
        const int rg = ks >> 3;
        const int k0 = (ks & 7) << 6;
        const unsigned short* As = (rg < 2) ? Ah : Al;
        const unsigned short* Bs = (rg == 1) ? Wl : Wh;
        #pragma unroll
        for (int j = 0; j < 6; ++j) {
            const int o  = (wid * 6 + j) << 10;
            const int li = o + lane * 16;
            const void* g;
            if (li < ABYTES) {
                const int r  = li >> 7;
                const int kb = (li & 127) ^ ((r & 7) << 4);
                g = As + (size_t)(m0 + r) * 512 + k0 + (kb >> 1);
            } else {
                const int lb = li - ABYTES;
                const int r  = lb >> 7;
                const int kb = (lb & 127) ^ ((r & 7) << 4);
                g = Bs + (size_t)(n0 + r) * 512 + k0 + (kb >> 1);
            }
            gload16(g, &lds[buf][o], lane);
        }
    };

    stage(0, 0);
    stage(1, 1);
    for (int ks = 0; ks < 24; ++ks) {
        const int cur = ks % 3;
        if (ks < 22) {
            stage((ks + 2) % 3, ks + 2);
            asm volatile("s_waitcnt vmcnt(12)" ::: "memory");
        } else if (ks == 22) {
            asm volatile("s_waitcnt vmcnt(6)" ::: "memory");
        } else {
            asm volatile("s_waitcnt vmcnt(0)" ::: "memory");
        }
        __builtin_amdgcn_s_barrier();
        #pragma unroll
        for (int ksub = 0; ksub < 2; ++ksub) {
            const int kbb = (ksub << 6) + ((lane >> 4) << 4);
            bf16frag af[4], bf[2];
            #pragma unroll
            for (int mt = 0; mt < 4; ++mt) {
                const int r = wr * 64 + mt * 16 + (lane & 15);
                af[mt] = *(const bf16frag*)(&lds[cur][0] + r * 128 + (kbb ^ ((r & 7) << 4)));
            }
            #pragma unroll
            for (int nt = 0; nt < 2; ++nt) {
                const int r = wc * 32 + nt * 16 + (lane & 15);
                bf[nt] = *(const bf16frag*)(&lds[cur][0] + ABYTES + r * 128 + (kbb ^ ((r & 7) << 4)));
            }
            #pragma unroll
            for (int mt = 0; mt < 4; ++mt)
                #pragma unroll
                for (int nt = 0; nt < 2; ++nt)
                    acc[mt][nt] = __builtin_amdgcn_mfma_f32_16x16x32_bf16(
                        af[mt], bf[nt], acc[mt][nt], 0, 0, 0);
        }
        __builtin_amdgcn_s_barrier();
    }

    const int rbase = (lane >> 4) * 4;
    #pragma unroll
    for (int mt = 0; mt < 4; ++mt)
        #pragma unroll
        for (int nt = 0; nt < 2; ++nt) {
            const int col = n0 + wc * 32 + nt * 16 + (lane & 15);
            #pragma unroll
            for (int j = 0; j < 4; ++j) {
                const int row = m0 + wr * 64 + mt * 16 + rbase + j;
                C[(size_t)row * 512 + col] = acc[mt][nt][j];
            }
        }
}

// ---- MFMA windowed attention (byte-identical to rounds 12-14, validated) ----
__global__ __launch_bounds__(128) void swattn5(
    const unsigned short* __restrict__ QH, const unsigned short* __restrict__ QL,
    const unsigned short* __restrict__ KH, const unsigned short* __restrict__ KL,
    const unsigned short* __restrict__ VTH, const unsigned short* __restrict__ VTL,
    unsigned short* __restrict__ OH, unsigned short* __restrict__ OL, int T)
{
    __shared__ unsigned short KsH[96 * 88], KsL[96 * 88];
    __shared__ unsigned short VtH[64 * 104], VtL[64 * 104];
    __shared__ unsigned short PsH[32 * 104], PsL[32 * 104];

    const int h   = blockIdx.x & 7;
    const int t0  = (blockIdx.x >> 3) * 32;
    const int kt0 = t0 - 63;
    const int tid = threadIdx.x;
    const int vtw = T + 64;

    {
        const int c = tid & 7;
        for (int r = tid >> 3; r < 96; r += 16) {
            const int kt = kt0 + r;
            u16x8 kh = {0,0,0,0,0,0,0,0}, kl = {0,0,0,0,0,0,0,0};
            if (kt >= 0 && r < 95) {
                const size_t off = (size_t)kt * 512 + h * 64 + c * 8;
                kh = *(const u16x8*)(KH + off);
                kl = *(const u16x8*)(KL + off);
            }
            *(u16x8*)&KsH[r * 88 + c * 8] = kh;
            *(u16x8*)&KsL[r * 88 + c * 8] = kl;
        }
    }
    for (int i = tid; i < 64 * 12; i += 128) {
        const int d = i / 12, c = i % 12;
        const size_t off = (size_t)(h * 64 + d) * vtw + t0 + c * 8;
        *(u16x8*)&VtH[d * 104 + c * 8] = *(const u16x8*)(VTH + off);
        *(u16x8*)&VtL[d * 104 + c * 8] = *(const u16x8*)(VTL + off);
    }
    __syncthreads();

    const int wid  = tid >> 6;
    const int lane = tid & 63;
    const int lr = lane & 15;
    const int lg = lane >> 4;

    bf16frag qfh[2], qfl[2];
    {
        const size_t base = (size_t)(t0 + wid * 16 + lr) * 512 + h * 64 + lg * 8;
        qfh[0] = *(const bf16frag*)(QH + base);
        qfh[1] = *(const bf16frag*)(QH + base + 32);
        qfl[0] = *(const bf16frag*)(QL + base);
        qfl[1] = *(const bf16frag*)(QL + base + 32);
    }

    f32x4 s[6];
    #pragma unroll
    for (int wt = 0; wt < 6; ++wt) s[wt] = (f32x4){0.f, 0.f, 0.f, 0.f};
    #pragma unroll
    for (int ksub = 0; ksub < 2; ++ksub) {
        #pragma unroll
        for (int wt = 0; wt < 6; ++wt) {
            const int a = (wt * 16 + lr) * 88 + lg * 8 + ksub * 32;
            bf16frag akh = *(const bf16frag*)&KsH[a];
            bf16frag akl = *(const bf16frag*)&KsL[a];
            s[wt] = __builtin_amdgcn_mfma_f32_16x16x32_bf16(akh, qfh[ksub], s[wt], 0, 0, 0);
            s[wt] = __builtin_amdgcn_mfma_f32_16x16x32_bf16(akh, qfl[ksub], s[wt], 0, 0, 0);
            s[wt] = __builtin_amdgcn_mfma_f32_16x16x32_bf16(akl, qfh[ksub], s[wt], 0, 0, 0);
        }
    }

    const int q_local = wid * 16 + lr;
    float sc[6][4];
    float mx = -3e38f;
    #pragma unroll
    for (int wt = 0; wt < 6; ++wt)
        #pragma unroll
        for (int j = 0; j < 4; ++j) {
            const int w = wt * 16 + lg * 4 + j;
            const bool valid = (w >= q_local) && (w <= q_local + 63) && (kt0 + w >= 0);
            sc[wt][j] = valid ? s[wt][j] * 0.125f : -3e38f;
            mx = fmaxf(mx, sc[wt][j]);
        }
    mx = fmaxf(mx, __shfl_xor(mx, 16));
    mx = fmaxf(mx, __shfl_xor(mx, 32));
    float sum = 0.f;
    #pragma unroll
    for (int wt = 0; wt < 6; ++wt)
        #pragma unroll
        for (int j = 0; j < 4; ++j) {
            sc[wt][j] = __expf(sc[wt][j] - mx);
            sum += sc[wt][j];
        }
    sum += __shfl_xor(sum, 16);
    sum += __shfl_xor(sum, 32);
    const float inv = 1.f / sum;

    #pragma unroll
    for (int wt = 0; wt < 6; ++wt) {
        ushort4 ph, pl;
        unsigned short hh, ll;
        split_val(sc[wt][0] * inv, hh, ll); ph.x = hh; pl.x = ll;
        split_val(sc[wt][1] * inv, hh, ll); ph.y = hh; pl.y = ll;
        split_val(sc[wt][2] * inv, hh, ll); ph.z = hh; pl.z = ll;
        split_val(sc[wt][3] * inv, hh, ll); ph.w = hh; pl.w = ll;
        const int col = wt * 16 + lg * 4;
        *(ushort4*)&PsH[q_local * 104 + col] = ph;
        *(ushort4*)&PsL[q_local * 104 + col] = pl;
    }

    f32x4 oa[4];
    #pragma unroll
    for (int dt = 0; dt < 4; ++dt) oa[dt] = (f32x4){0.f, 0.f, 0.f, 0.f};
    #pragma unroll
    for (int ks = 0; ks < 3; ++ks) {
        const int ka = lg * 8 + ks * 32;
        bf16frag pah = *(const bf16frag*)&PsH[(wid * 16 + lr) * 104 + ka];
        bf16frag pal = *(const bf16frag*)&PsL[(wid * 16 + lr) * 104 + ka];
        #pragma unroll
        for (int dt = 0; dt < 4; ++dt) {
            const int a = (dt * 16 + lr) * 104 + ka;
            bf16frag bvh = *(const bf16frag*)&VtH[a];
            bf16frag bvl = *(const bf16frag*)&VtL[a];
            oa[dt] = __builtin_amdgcn_mfma_f32_16x16x32_bf16(pah, bvh, oa[dt], 0, 0, 0);
            oa[dt] = __builtin_amdgcn_mfma_f32_16x16x32_bf16(pal, bvh, oa[dt], 0, 0, 0);
            oa[dt] = __builtin_amdgcn_mfma_f32_16x16x32_bf16(pah, bvl, oa[dt], 0, 0, 0);
        }
    }

    #pragma unroll
    for (int dt = 0; dt < 4; ++dt) {
        const int d = dt * 16 + lr;
        #pragma unroll
        for (int j = 0; j < 4; ++j) {
            const int t = t0 + wid * 16 + lg * 4 + j;
            unsigned short hh, ll;
            split_val(oa[dt][j], hh, ll);
            const size_t oi = (size_t)t * 512 + h * 64 + d;
            OH[oi] = hh;
            OL[oi] = ll;
        }
    }
}

extern "C" void kernel_launch(void* const* d_in, const int* in_sizes, int n_in,
                              void* d_out, int out_size, void* d_ws, size_t ws_size,
                              hipStream_t stream) {
    const float* x  = (const float*)d_in[0];
    const float* Wq = (const float*)d_in[1];
    const float* Wk = (const float*)d_in[2];
    const float* Wv = (const float*)d_in[3];
    const float* Wo = (const float*)d_in[4];
    float* out = (float*)d_out;

    const int D = 512;
    const int T = in_sizes[0] / D;        // 4096
    const size_t tdf = (size_t)T * D;
    const size_t wsz = (size_t)D * D;
    const int vtw = T + 64;
    const size_t vts = (size_t)D * vtw;

    unsigned short* qh  = (unsigned short*)d_ws;
    unsigned short* ql  = qh + tdf;
    unsigned short* kh  = ql + tdf;
    unsigned short* kl  = kh + tdf;
    unsigned short* vth = kl + tdf;
    unsigned short* vtl = vth + vts;
    unsigned short* abh = vtl + vts;
    unsigned short* abl = abh + tdf;
    unsigned short* xh  = abl + tdf;
    unsigned short* xl  = xh + tdf;
    unsigned short* wqh = xl + tdf;
    unsigned short* wql = wqh + wsz;
    unsigned short* wkh = wql + wsz;
    unsigned short* wkl = wkh + wsz;
    unsigned short* wvh = wkl + wsz;
    unsigned short* wvl = wvh + wsz;
    unsigned short* woh = wvl + wsz;
    unsigned short* wol = woh + wsz;
    // ws use ≈ 46 MB

    dim3 blk(256);
    split5<<<dim3(256, 1, 5), blk, 0, stream>>>(
        x, Wq, Wk, Wv, Wo, xh, xl, wqh, wql, wkh, wkl, wvh, wvl, woh, wol,
        (int)tdf, (int)wsz);

    // fused Q/K/V^T: 768 blocks (divisible by 8 for the swizzle)
    const int NQK = 8 * (T / 128);
    const int NVT = (T / 64) * (D / 128);
    gemm_qkvt<<<dim3(2 * NQK + NVT), blk, 0, stream>>>(
        xh, xl, wqh, wql, wkh, wkl, wvh, wvl,
        qh, ql, kh, kl, vth, vtl, T, vtw);

    // attention: 1024 blocks x 128 thr
    swattn5<<<dim3(8 * T / 32), dim3(128), 0, stream>>>(
        qh, ql, kh, kl, vth, vtl, abh, abl, T);

    // out-proj: BM=128 -> 256 blocks (divisible by 8)
    gemm_out<<<dim3((T / 128) * (D / 64)), blk, 0, stream>>>(
        abh, abl, woh, wol, out, T);
}